// Round 6
// baseline (99.325 us; speedup 1.0000x reference)
//
#include <hip/hip_runtime.h>
#include <hip/hip_bf16.h>

// ---------------- types ----------------
typedef __bf16 bf16x8 __attribute__((ext_vector_type(8)));
typedef float  f32x4  __attribute__((ext_vector_type(4)));
typedef unsigned short u16x8 __attribute__((ext_vector_type(8)));

#define NTOK 16384      // B*S
#define SEQ  4096
#define DIM  128
#define NSEG 13         // 1 g-segment + 12 f-segments
#define NM   12
#define NK   13

// round-to-nearest-even f32 -> bf16 bits
__device__ inline unsigned short f2bf(float f) {
    unsigned int u = __float_as_uint(f);
    unsigned int r = (u + 0x7FFFu + ((u >> 16) & 1u)) >> 16;
    return (unsigned short)r;
}
__device__ inline float bf2f(unsigned short h) {
    return __uint_as_float(((unsigned int)h) << 16);
}
__device__ inline float uaf(unsigned int u) { return __uint_as_float(u); }
// packed f32x2 -> bf16x2 (lo=a, hi=b), RNE (same as f2bf)
__device__ inline unsigned int cvtpk(float a, float b) {
    unsigned int r;
    asm("v_cvt_pk_bf16_f32 %0, %1, %2" : "=v"(r) : "v"(a), "v"(b));
    return r;
}

// 5-op gelu, CORRECT small-|u| form (leading correction is QUADRATIC):
//   gelu(u) = 0.5u + u^2*(c0 + u^2*c1 + u^4*c2),  c0=0.5*sqrt(2/pi), c1=-c0/6, c2=c0/40
__device__ inline float gelu_f(float u) {
    const float c0 = 0.3989422804f;
    const float c1 = -0.0664903801f;
    const float c2 = 0.0099735570f;
    float u2 = u * u;
    float p  = __builtin_fmaf(u2, c2, c1);
    p        = __builtin_fmaf(u2, p, c0);
    return __builtin_fmaf(u2, p, 0.5f * u);
}

// LDS XOR-swizzle: rows are 256B (128 u16). XOR byte bits [4:6] with row bits [8:10].
__device__ inline int swz(int u16idx) {
    int byte = u16idx << 1;
    byte ^= ((byte >> 8) & 7) << 4;
    return byte >> 1;
}

// ---------------- kernel 1: fused embed (x = emb[data]+apc -> bf16) + weight conv ----------------
#define EMB_BLOCKS 8192                         // 2 rows per 256-thread block
#define CONV_BLOCKS ((NSEG * DIM * DIM + 255) / 256)
__global__ __launch_bounds__(256) void prep_kernel(
    const int* __restrict__ data, const float* __restrict__ emb,
    const float* __restrict__ apc, unsigned short* __restrict__ xb,
    const float* __restrict__ g_W1, const float* __restrict__ g_W2,
    const float* __restrict__ f_W1, const float* __restrict__ f_W2,
    unsigned short* __restrict__ wb1T, unsigned short* __restrict__ wb2Tg,
    unsigned short* __restrict__ wb2Tf)
{
    int tid = threadIdx.x;
    if (blockIdx.x < EMB_BLOCKS) {
        int n = blockIdx.x * 2 + (tid >> 7);
        int d = tid & 127;
        int s = n & (SEQ - 1);
        int tok = data[n];
        float v = emb[(size_t)tok * DIM + d] + apc[s * DIM + d];
        xb[(size_t)n * DIM + d] = f2bf(v);
    } else {
        int i = (blockIdx.x - EMB_BLOCKS) * 256 + tid;
        if (i < NSEG * DIM * DIM) {
            int seg = i >> 14;
            int e = (i >> 7) & 127;
            int d = i & 127;
            float v = (seg == 0) ? g_W1[d * DIM + e]
                                 : f_W1[((seg - 1) * DIM + d) * DIM + e];
            wb1T[i] = f2bf(v);
        }
        if (i < DIM * DIM) {
            int c = i >> 7, e = i & 127;
            wb2Tg[i] = f2bf(g_W2[e * DIM + c]);
        }
        if (i < NM * 16 * DIM) {
            int m = i >> 11;
            int c = (i >> 7) & 15;
            int e = i & 127;
            float v = (c < NK) ? f_W2[(m * DIM + e) * NK + c] : 0.f;
            wb2Tf[i] = f2bf(v);
        }
    }
}

// ---------------- kernel 2: fused MLP — W in LDS (reused 32x), X direct from global ----------------
__global__ __launch_bounds__(256, 3) void mlp_kernel(
    const unsigned short* __restrict__ xb,
    const unsigned short* __restrict__ wb1T,
    const unsigned short* __restrict__ wb2Tg,
    const unsigned short* __restrict__ wb2Tf,
    const float* __restrict__ g_b1, const float* __restrict__ g_b2,
    const float* __restrict__ f_b1, const float* __restrict__ f_b2,
    float* __restrict__ resF, unsigned short* __restrict__ resB,
    unsigned short* __restrict__ Wallb)
{
    const int seg  = blockIdx.y;           // 0 => g ; 1..12 => f[seg-1]
    const int row0 = blockIdx.x * 64;
    const int tid  = threadIdx.x;
    const int wave = tid >> 6;             // 0..3
    const int lane = tid & 63;

    __shared__ __align__(16) unsigned short Hs[4][16 * DIM];  // 16 KB wave-private strips
    __shared__ __align__(16) unsigned short W1s[DIM * DIM];   // 32 KB
    __shared__ __align__(16) unsigned short W2fs[16 * DIM];   // 4 KB

    const int r16   = lane & 15;
    const int kgrp  = (lane >> 4) * 8;
    const int crow0 = (lane >> 4) << 2;    // strip-local C row base

    // biases into registers (overlaps staging)
    const float* b1p = (seg == 0) ? g_b1 : (f_b1 + (seg - 1) * DIM);
    float bias1[8];
    #pragma unroll
    for (int t = 0; t < 8; ++t) bias1[t] = b1p[t * 16 + r16];
    float bias2[8];
    float bias2f = 0.f;
    if (seg == 0) {
        #pragma unroll
        for (int t = 0; t < 8; ++t) bias2[t] = g_b2[t * 16 + r16];
    } else {
        bias2f = (r16 < NK) ? f_b2[(seg - 1) * NK + r16] : 0.f;
    }

    // stage W1T (128x128) swizzled
    {
        const int4* wg = reinterpret_cast<const int4*>(wb1T + (size_t)seg * DIM * DIM);
        #pragma unroll
        for (int i = 0; i < 8; ++i)
            *reinterpret_cast<int4*>(&W1s[swz((tid + i * 256) * 8)]) = wg[tid + i * 256];
    }
    // stage W2f (16x128) swizzled — f-segments only
    if (seg != 0) {
        const int4* wg = reinterpret_cast<const int4*>(wb2Tf + (size_t)(seg - 1) * 16 * DIM);
        *reinterpret_cast<int4*>(&W2fs[swz(tid * 8)]) = wg[tid];
    }
    __syncthreads();   // the ONLY barrier (waits on W staging only)

    // ---- layer 1: acc = X @ W1 ; A direct from global, B from LDS ----
    const unsigned short* xrow = xb + (size_t)(row0 + wave * 16 + r16) * DIM + kgrp;
    f32x4 acc[8];
    #pragma unroll
    for (int t = 0; t < 8; ++t) acc[t] = (f32x4){0.f, 0.f, 0.f, 0.f};
    #pragma unroll
    for (int kk = 0; kk < 4; ++kk) {
        bf16x8 a = *reinterpret_cast<const bf16x8*>(xrow + kk * 32);
        #pragma unroll
        for (int t = 0; t < 8; ++t) {
            bf16x8 b = *reinterpret_cast<const bf16x8*>(&W1s[swz((t * 16 + r16) * DIM + kk * 32 + kgrp)]);
            acc[t] = __builtin_amdgcn_mfma_f32_16x16x32_bf16(a, b, acc[t], 0, 0, 0);
        }
    }

    // ---- gelu -> H into this wave's own swizzled strip (cvt_pk pairs) ----
    unsigned short* hs = Hs[wave];
    #pragma unroll
    for (int t = 0; t < 8; ++t) {
        int col = t * 16 + r16;
        #pragma unroll
        for (int r = 0; r < 4; r += 2) {
            float g0 = gelu_f(acc[t][r]     + bias1[t]);
            float g1 = gelu_f(acc[t][r + 1] + bias1[t]);
            unsigned int pk = cvtpk(g0, g1);
            hs[swz((crow0 + r)     * DIM + col)] = (unsigned short)pk;
            hs[swz((crow0 + r + 1) * DIM + col)] = (unsigned short)(pk >> 16);
        }
    }

    // ---- layer 2 ----
    if (seg == 0) {
        f32x4 acc2[8];
        #pragma unroll
        for (int t = 0; t < 8; ++t) acc2[t] = (f32x4){0.f, 0.f, 0.f, 0.f};
        #pragma unroll
        for (int kk = 0; kk < 4; ++kk) {
            bf16x8 a = *reinterpret_cast<const bf16x8*>(&hs[swz(r16 * DIM + kk * 32 + kgrp)]);
            #pragma unroll
            for (int t = 0; t < 8; ++t) {
                bf16x8 b = *reinterpret_cast<const bf16x8*>(wb2Tg + (size_t)(t * 16 + r16) * DIM + kk * 32 + kgrp);
                acc2[t] = __builtin_amdgcn_mfma_f32_16x16x32_bf16(a, b, acc2[t], 0, 0, 0);
            }
        }
        #pragma unroll
        for (int t = 0; t < 8; ++t) {
            int col = t * 16 + r16;
            #pragma unroll
            for (int r = 0; r < 4; r += 2) {
                int grow = row0 + wave * 16 + crow0 + r;
                float v0 = acc2[t][r]     + bias2[t];
                float v1 = acc2[t][r + 1] + bias2[t];
                resF[(size_t)grow * DIM + col]       = v0;
                resF[(size_t)(grow + 1) * DIM + col] = v1;
                unsigned int pk = cvtpk(v0, v1);
                resB[(size_t)grow * DIM + col]       = (unsigned short)pk;
                resB[(size_t)(grow + 1) * DIM + col] = (unsigned short)(pk >> 16);
            }
        }
    } else {
        int m = seg - 1;
        f32x4 acc2 = (f32x4){0.f, 0.f, 0.f, 0.f};
        #pragma unroll
        for (int kk = 0; kk < 4; ++kk) {
            bf16x8 a = *reinterpret_cast<const bf16x8*>(&hs[swz(r16 * DIM + kk * 32 + kgrp)]);
            bf16x8 b = *reinterpret_cast<const bf16x8*>(&W2fs[swz(r16 * DIM + kk * 32 + kgrp)]);
            acc2 = __builtin_amdgcn_mfma_f32_16x16x32_bf16(a, b, acc2, 0, 0, 0);
        }
        #pragma unroll
        for (int r = 0; r < 4; r += 2) {
            int grow = row0 + wave * 16 + crow0 + r;
            unsigned int pk = cvtpk(acc2[r] + bias2f, acc2[r + 1] + bias2f);
            Wallb[((size_t)m * NTOK + grow) * 16 + r16]     = (unsigned short)pk;
            Wallb[((size_t)m * NTOK + grow + 1) * 16 + r16] = (unsigned short)(pk >> 16);
        }
    }
}

// ---------------- kernel 3: ALL 12 scan steps, V slice in LDS, consecutive-token b128 taps --------
// Block = (batch, 2-channel chunk), batch pinned to an XCD pair (bb=(bid>>1)&3).
// Thread owns 4 CONSECUTIVE tokens (t0=4*tid): each chord tap for all 4 tokens is ONE
// aligned ds_read_b128; taps k=0..3 come from an 8-word window (2 b128 + register reuse).
// LDS ops/thread/step: ~11 b128 reads + 1-2 b128 writes (was 52+6 b32).
// W(m+1) prefetched into registers during step m. Ring pad (2048 tokens) keeps all
// offsets immediate. Numerics bit-identical to the proven path: bf16 V carry (RNE cvtpk),
// bf16 res steps 0..10, f32 resF + f32 out at step 11, same k-order FMA chain.
#define CCH 2
#define PADTOK (SEQ + 2048)             // 6144 tokens incl ring pad
__global__ __launch_bounds__(1024) void scan_lds_kernel(
    const unsigned short* __restrict__ resB,
    const float* __restrict__ resF,
    const unsigned short* __restrict__ Wallb,   // [NM][NTOK][16]
    float* __restrict__ outF)
{
    __shared__ __align__(16) unsigned int V32[2 * PADTOK];   // 48 KB

    const int bid = (int)blockIdx.x;
    const int bb    = (bid >> 1) & 3;                 // batch -> XCD pair
    const int chunk = ((bid >> 3) << 1) | (bid & 1);  // 0..63
    const int d0  = chunk * CCH;
    const int tid = threadIdx.x;                      // 0..1023
    const int t0  = tid * 4;                          // first owned token

    // ---- one-time: packed res regs + seed V0 (with ring pad) ----
    unsigned int resP[4];
    {
        uint4 sv;
        #pragma unroll
        for (int j = 0; j < 4; ++j) {
            int n = (bb << 12) + t0 + j;
            unsigned int r = *reinterpret_cast<const unsigned int*>(resB + (size_t)n * DIM + d0);
            resP[j] = r;
            ((unsigned int*)&sv)[j] = r;
        }
        *reinterpret_cast<uint4*>(&V32[t0]) = sv;
        if (t0 < 2048) *reinterpret_cast<uint4*>(&V32[t0 + SEQ]) = sv;
    }

    const unsigned short* wb0 = Wallb + (size_t)(bb << 12) * 16;

    // ---- preload W for step 0 (rows t0..t0+3: 64B contiguous per thread) ----
    uint4 wA[4][2];
    #pragma unroll
    for (int j = 0; j < 4; ++j) {
        const uint4* wrow = reinterpret_cast<const uint4*>(wb0 + (size_t)(t0 + j) * 16);
        wA[j][0] = wrow[0]; wA[j][1] = wrow[1];
    }
    __syncthreads();

    unsigned int curbase = 0;

    // ---- steps 0..10: bf16 V carry in LDS; W(m+1) prefetched during compute ----
    #pragma unroll 1
    for (int m = 0; m < NM - 1; ++m) {
        // issue next step's W loads first (consumed after compute -> latency hidden)
        uint4 wN[4][2];
        {
            const unsigned short* wpn = wb0 + (size_t)(m + 1) * NTOK * 16;
            #pragma unroll
            for (int j = 0; j < 4; ++j) {
                const uint4* wrow = reinterpret_cast<const uint4*>(wpn + (size_t)(t0 + j) * 16);
                wN[j][0] = wrow[0]; wN[j][1] = wrow[1];
            }
        }

        const unsigned int nb = curbase ^ PADTOK;
        const unsigned int* vb = &V32[curbase + t0];

        float o0[4], o1[4];
        #pragma unroll
        for (int j = 0; j < 4; ++j) {
            o0[j] = uaf(resP[j] << 16);
            o1[j] = uaf(resP[j] & 0xffff0000u);
        }

        uint4 Ra = *reinterpret_cast<const uint4*>(vb);       // window 0..3
        uint4 Rb = *reinterpret_cast<const uint4*>(vb + 4);   // window 4..7

        #pragma unroll
        for (int k = 0; k < NK; ++k) {
            unsigned int v0, v1, v2, v3;
            if (k == 0)      { v0 = Ra.x; v1 = Ra.y; v2 = Ra.z; v3 = Ra.w; }
            else if (k == 1) { v0 = Ra.y; v1 = Ra.z; v2 = Ra.w; v3 = Rb.x; }
            else if (k == 2) { v0 = Ra.z; v1 = Ra.w; v2 = Rb.x; v3 = Rb.y; }
            else if (k == 3) { v0 = Rb.x; v1 = Rb.y; v2 = Rb.z; v3 = Rb.w; }
            else {
                uint4 g = *reinterpret_cast<const uint4*>(vb + (8 << (k - 4)));
                v0 = g.x; v1 = g.y; v2 = g.z; v3 = g.w;
            }
            #pragma unroll
            for (int j = 0; j < 4; ++j) {
                uint4 wa = wA[j][0], wbv = wA[j][1];
                unsigned int ww =
                    (k < 2) ? wa.x : (k < 4) ? wa.y : (k < 6) ? wa.z : (k < 8) ? wa.w :
                    (k < 10) ? wbv.x : (k < 12) ? wbv.y : wbv.z;
                float w = (k & 1) ? uaf(ww & 0xffff0000u) : uaf(ww << 16);
                unsigned int v = (j == 0) ? v0 : (j == 1) ? v1 : (j == 2) ? v2 : v3;
                o0[j] = __builtin_fmaf(w, uaf(v << 16),          o0[j]);
                o1[j] = __builtin_fmaf(w, uaf(v & 0xffff0000u), o1[j]);
            }
        }

        uint4 ov;
        ov.x = cvtpk(o0[0], o1[0]);
        ov.y = cvtpk(o0[1], o1[1]);
        ov.z = cvtpk(o0[2], o1[2]);
        ov.w = cvtpk(o0[3], o1[3]);
        *reinterpret_cast<uint4*>(&V32[nb + t0]) = ov;
        if (t0 < 2048) *reinterpret_cast<uint4*>(&V32[nb + t0 + SEQ]) = ov;

        // rotate prefetched W into place (vmcnt wait lands here, after compute)
        #pragma unroll
        for (int j = 0; j < 4; ++j) { wA[j][0] = wN[j][0]; wA[j][1] = wN[j][1]; }
        __syncthreads();
        curbase = nb;
    }

    // ---- final step m=11: f32 res, f32 out; W already in wA ----
    {
        const unsigned int* vb = &V32[curbase + t0];

        float o0[4], o1[4];
        #pragma unroll
        for (int j = 0; j < 4; ++j) {
            int n = (bb << 12) + t0 + j;
            float2 rf = *reinterpret_cast<const float2*>(resF + (size_t)n * DIM + d0);
            o0[j] = rf.x; o1[j] = rf.y;
        }

        uint4 Ra = *reinterpret_cast<const uint4*>(vb);
        uint4 Rb = *reinterpret_cast<const uint4*>(vb + 4);

        #pragma unroll
        for (int k = 0; k < NK; ++k) {
            unsigned int v0, v1, v2, v3;
            if (k == 0)      { v0 = Ra.x; v1 = Ra.y; v2 = Ra.z; v3 = Ra.w; }
            else if (k == 1) { v0 = Ra.y; v1 = Ra.z; v2 = Ra.w; v3 = Rb.x; }
            else if (k == 2) { v0 = Ra.z; v1 = Ra.w; v2 = Rb.x; v3 = Rb.y; }
            else if (k == 3) { v0 = Rb.x; v1 = Rb.y; v2 = Rb.z; v3 = Rb.w; }
            else {
                uint4 g = *reinterpret_cast<const uint4*>(vb + (8 << (k - 4)));
                v0 = g.x; v1 = g.y; v2 = g.z; v3 = g.w;
            }
            #pragma unroll
            for (int j = 0; j < 4; ++j) {
                uint4 wa = wA[j][0], wbv = wA[j][1];
                unsigned int ww =
                    (k < 2) ? wa.x : (k < 4) ? wa.y : (k < 6) ? wa.z : (k < 8) ? wa.w :
                    (k < 10) ? wbv.x : (k < 12) ? wbv.y : wbv.z;
                float w = (k & 1) ? uaf(ww & 0xffff0000u) : uaf(ww << 16);
                unsigned int v = (j == 0) ? v0 : (j == 1) ? v1 : (j == 2) ? v2 : v3;
                o0[j] = __builtin_fmaf(w, uaf(v << 16),          o0[j]);
                o1[j] = __builtin_fmaf(w, uaf(v & 0xffff0000u), o1[j]);
            }
        }

        #pragma unroll
        for (int j = 0; j < 4; ++j) {
            int n = (bb << 12) + t0 + j;
            float2 o; o.x = o0[j]; o.y = o1[j];
            *reinterpret_cast<float2*>(outF + (size_t)n * DIM + d0) = o;
        }
    }
}

// ---------------- launch ----------------
extern "C" void kernel_launch(void* const* d_in, const int* in_sizes, int n_in,
                              void* d_out, int out_size, void* d_ws, size_t ws_size,
                              hipStream_t stream) {
    const int*   data = (const int*)  d_in[0];
    const float* emb  = (const float*)d_in[2];
    const float* apc  = (const float*)d_in[3];
    const float* g_W1 = (const float*)d_in[4];
    const float* g_b1 = (const float*)d_in[5];
    const float* g_W2 = (const float*)d_in[6];
    const float* g_b2 = (const float*)d_in[7];
    const float* f_W1 = (const float*)d_in[8];
    const float* f_b1 = (const float*)d_in[9];
    const float* f_W2 = (const float*)d_in[10];
    const float* f_b2 = (const float*)d_in[11];
    float* out = (float*)d_out;

    char* ws = (char*)d_ws;
    size_t off = 0;
    auto alloc = [&](size_t bytes) {
        void* p = ws + off;
        off += (bytes + 255) & ~(size_t)255;
        return p;
    };
    unsigned short* xb    = (unsigned short*)alloc((size_t)NTOK * DIM * 2);
    unsigned short* wb1T  = (unsigned short*)alloc((size_t)NSEG * DIM * DIM * 2);
    unsigned short* wb2Tg = (unsigned short*)alloc((size_t)DIM * DIM * 2);
    unsigned short* wb2Tf = (unsigned short*)alloc((size_t)NM * 16 * DIM * 2);
    float*          resF  = (float*)alloc((size_t)NTOK * DIM * 4);
    unsigned short* resB  = (unsigned short*)alloc((size_t)NTOK * DIM * 2);
    unsigned short* Wallb = (unsigned short*)alloc((size_t)NM * NTOK * 16 * 2);
    (void)ws_size; (void)in_sizes; (void)n_in; (void)out_size;

    prep_kernel<<<EMB_BLOCKS + CONV_BLOCKS, 256, 0, stream>>>(
        data, emb, apc, xb, g_W1, g_W2, f_W1, f_W2, wb1T, wb2Tg, wb2Tf);

    dim3 grid(NTOK / 64, NSEG);
    mlp_kernel<<<grid, 256, 0, stream>>>(xb, wb1T, wb2Tg, wb2Tf,
                                         g_b1, g_b2, f_b1, f_b2, resF, resB, Wallb);

    // all 12 scan steps in one kernel: V channel-slices live in LDS (ring-padded),
    // consecutive-token b128 gathers, W software-pipelined, batch pinned to XCD pair
    scan_lds_kernel<<<256, 1024, 0, stream>>>(resB, resF, Wallb, out);
}

// Round 8
// 76.588 us; speedup vs baseline: 1.2969x; 1.2969x over previous
//
#include <hip/hip_runtime.h>
#include <hip/hip_bf16.h>

// ---------------- types ----------------
typedef __bf16 bf16x8 __attribute__((ext_vector_type(8)));
typedef float  f32x4  __attribute__((ext_vector_type(4)));
typedef unsigned short u16x8 __attribute__((ext_vector_type(8)));

#define NTOK 16384      // B*S
#define SEQ  4096
#define DIM  128
#define NSEG 13         // 1 g-segment + 12 f-segments
#define NM   12
#define NK   13

// round-to-nearest-even f32 -> bf16 bits
__device__ inline unsigned short f2bf(float f) {
    unsigned int u = __float_as_uint(f);
    unsigned int r = (u + 0x7FFFu + ((u >> 16) & 1u)) >> 16;
    return (unsigned short)r;
}
__device__ inline float bf2f(unsigned short h) {
    return __uint_as_float(((unsigned int)h) << 16);
}
__device__ inline float uaf(unsigned int u) { return __uint_as_float(u); }
// packed f32x2 -> bf16x2 (lo=a, hi=b), RNE (same as f2bf)
__device__ inline unsigned int cvtpk(float a, float b) {
    unsigned int r;
    asm("v_cvt_pk_bf16_f32 %0, %1, %2" : "=v"(r) : "v"(a), "v"(b));
    return r;
}

// 5-op gelu, CORRECT small-|u| form (leading correction is QUADRATIC):
//   gelu(u) = 0.5u + u^2*(c0 + u^2*c1 + u^4*c2),  c0=0.5*sqrt(2/pi), c1=-c0/6, c2=c0/40
__device__ inline float gelu_f(float u) {
    const float c0 = 0.3989422804f;
    const float c1 = -0.0664903801f;
    const float c2 = 0.0099735570f;
    float u2 = u * u;
    float p  = __builtin_fmaf(u2, c2, c1);
    p        = __builtin_fmaf(u2, p, c0);
    return __builtin_fmaf(u2, p, 0.5f * u);
}

// LDS XOR-swizzle: rows are 256B (128 u16). XOR byte bits [4:6] with row bits [8:10].
__device__ inline int swz(int u16idx) {
    int byte = u16idx << 1;
    byte ^= ((byte >> 8) & 7) << 4;
    return byte >> 1;
}

// ---------------- kernel 1: fused embed (x = emb[data]+apc -> bf16) + weight conv ----------------
#define EMB_BLOCKS 8192                         // 2 rows per 256-thread block
#define CONV_BLOCKS ((NSEG * DIM * DIM + 255) / 256)
__global__ __launch_bounds__(256) void prep_kernel(
    const int* __restrict__ data, const float* __restrict__ emb,
    const float* __restrict__ apc, unsigned short* __restrict__ xb,
    const float* __restrict__ g_W1, const float* __restrict__ g_W2,
    const float* __restrict__ f_W1, const float* __restrict__ f_W2,
    unsigned short* __restrict__ wb1T, unsigned short* __restrict__ wb2Tg,
    unsigned short* __restrict__ wb2Tf)
{
    int tid = threadIdx.x;
    if (blockIdx.x < EMB_BLOCKS) {
        int n = blockIdx.x * 2 + (tid >> 7);
        int d = tid & 127;
        int s = n & (SEQ - 1);
        int tok = data[n];
        float v = emb[(size_t)tok * DIM + d] + apc[s * DIM + d];
        xb[(size_t)n * DIM + d] = f2bf(v);
    } else {
        int i = (blockIdx.x - EMB_BLOCKS) * 256 + tid;
        if (i < NSEG * DIM * DIM) {
            int seg = i >> 14;
            int e = (i >> 7) & 127;
            int d = i & 127;
            float v = (seg == 0) ? g_W1[d * DIM + e]
                                 : f_W1[((seg - 1) * DIM + d) * DIM + e];
            wb1T[i] = f2bf(v);
        }
        if (i < DIM * DIM) {
            int c = i >> 7, e = i & 127;
            wb2Tg[i] = f2bf(g_W2[e * DIM + c]);
        }
        if (i < NM * 16 * DIM) {
            int m = i >> 11;
            int c = (i >> 7) & 15;
            int e = i & 127;
            float v = (c < NK) ? f_W2[(m * DIM + e) * NK + c] : 0.f;
            wb2Tf[i] = f2bf(v);
        }
    }
}

// ---------------- kernel 2: fused MLP — W in LDS (reused 32x), X direct from global ----------------
__global__ __launch_bounds__(256, 3) void mlp_kernel(
    const unsigned short* __restrict__ xb,
    const unsigned short* __restrict__ wb1T,
    const unsigned short* __restrict__ wb2Tg,
    const unsigned short* __restrict__ wb2Tf,
    const float* __restrict__ g_b1, const float* __restrict__ g_b2,
    const float* __restrict__ f_b1, const float* __restrict__ f_b2,
    float* __restrict__ resF, unsigned short* __restrict__ resB,
    unsigned short* __restrict__ Wallb)
{
    const int seg  = blockIdx.y;           // 0 => g ; 1..12 => f[seg-1]
    const int row0 = blockIdx.x * 64;
    const int tid  = threadIdx.x;
    const int wave = tid >> 6;             // 0..3
    const int lane = tid & 63;

    __shared__ __align__(16) unsigned short Hs[4][16 * DIM];  // 16 KB wave-private strips
    __shared__ __align__(16) unsigned short W1s[DIM * DIM];   // 32 KB
    __shared__ __align__(16) unsigned short W2fs[16 * DIM];   // 4 KB

    const int r16   = lane & 15;
    const int kgrp  = (lane >> 4) * 8;
    const int crow0 = (lane >> 4) << 2;    // strip-local C row base

    // biases into registers (overlaps staging)
    const float* b1p = (seg == 0) ? g_b1 : (f_b1 + (seg - 1) * DIM);
    float bias1[8];
    #pragma unroll
    for (int t = 0; t < 8; ++t) bias1[t] = b1p[t * 16 + r16];
    float bias2[8];
    float bias2f = 0.f;
    if (seg == 0) {
        #pragma unroll
        for (int t = 0; t < 8; ++t) bias2[t] = g_b2[t * 16 + r16];
    } else {
        bias2f = (r16 < NK) ? f_b2[(seg - 1) * NK + r16] : 0.f;
    }

    // stage W1T (128x128) swizzled
    {
        const int4* wg = reinterpret_cast<const int4*>(wb1T + (size_t)seg * DIM * DIM);
        #pragma unroll
        for (int i = 0; i < 8; ++i)
            *reinterpret_cast<int4*>(&W1s[swz((tid + i * 256) * 8)]) = wg[tid + i * 256];
    }
    // stage W2f (16x128) swizzled — f-segments only
    if (seg != 0) {
        const int4* wg = reinterpret_cast<const int4*>(wb2Tf + (size_t)(seg - 1) * 16 * DIM);
        *reinterpret_cast<int4*>(&W2fs[swz(tid * 8)]) = wg[tid];
    }
    __syncthreads();   // the ONLY barrier (waits on W staging only)

    // ---- layer 1: acc = X @ W1 ; A direct from global, B from LDS ----
    const unsigned short* xrow = xb + (size_t)(row0 + wave * 16 + r16) * DIM + kgrp;
    f32x4 acc[8];
    #pragma unroll
    for (int t = 0; t < 8; ++t) acc[t] = (f32x4){0.f, 0.f, 0.f, 0.f};
    #pragma unroll
    for (int kk = 0; kk < 4; ++kk) {
        bf16x8 a = *reinterpret_cast<const bf16x8*>(xrow + kk * 32);
        #pragma unroll
        for (int t = 0; t < 8; ++t) {
            bf16x8 b = *reinterpret_cast<const bf16x8*>(&W1s[swz((t * 16 + r16) * DIM + kk * 32 + kgrp)]);
            acc[t] = __builtin_amdgcn_mfma_f32_16x16x32_bf16(a, b, acc[t], 0, 0, 0);
        }
    }

    // ---- gelu -> H into this wave's own swizzled strip (cvt_pk pairs) ----
    unsigned short* hs = Hs[wave];
    #pragma unroll
    for (int t = 0; t < 8; ++t) {
        int col = t * 16 + r16;
        #pragma unroll
        for (int r = 0; r < 4; r += 2) {
            float g0 = gelu_f(acc[t][r]     + bias1[t]);
            float g1 = gelu_f(acc[t][r + 1] + bias1[t]);
            unsigned int pk = cvtpk(g0, g1);
            hs[swz((crow0 + r)     * DIM + col)] = (unsigned short)pk;
            hs[swz((crow0 + r + 1) * DIM + col)] = (unsigned short)(pk >> 16);
        }
    }

    // ---- layer 2 ----
    if (seg == 0) {
        f32x4 acc2[8];
        #pragma unroll
        for (int t = 0; t < 8; ++t) acc2[t] = (f32x4){0.f, 0.f, 0.f, 0.f};
        #pragma unroll
        for (int kk = 0; kk < 4; ++kk) {
            bf16x8 a = *reinterpret_cast<const bf16x8*>(&hs[swz(r16 * DIM + kk * 32 + kgrp)]);
            #pragma unroll
            for (int t = 0; t < 8; ++t) {
                bf16x8 b = *reinterpret_cast<const bf16x8*>(wb2Tg + (size_t)(t * 16 + r16) * DIM + kk * 32 + kgrp);
                acc2[t] = __builtin_amdgcn_mfma_f32_16x16x32_bf16(a, b, acc2[t], 0, 0, 0);
            }
        }
        #pragma unroll
        for (int t = 0; t < 8; ++t) {
            int col = t * 16 + r16;
            #pragma unroll
            for (int r = 0; r < 4; r += 2) {
                int grow = row0 + wave * 16 + crow0 + r;
                float v0 = acc2[t][r]     + bias2[t];
                float v1 = acc2[t][r + 1] + bias2[t];
                resF[(size_t)grow * DIM + col]       = v0;
                resF[(size_t)(grow + 1) * DIM + col] = v1;
                unsigned int pk = cvtpk(v0, v1);
                resB[(size_t)grow * DIM + col]       = (unsigned short)pk;
                resB[(size_t)(grow + 1) * DIM + col] = (unsigned short)(pk >> 16);
            }
        }
    } else {
        int m = seg - 1;
        f32x4 acc2 = (f32x4){0.f, 0.f, 0.f, 0.f};
        #pragma unroll
        for (int kk = 0; kk < 4; ++kk) {
            bf16x8 a = *reinterpret_cast<const bf16x8*>(&hs[swz(r16 * DIM + kk * 32 + kgrp)]);
            bf16x8 b = *reinterpret_cast<const bf16x8*>(&W2fs[swz(r16 * DIM + kk * 32 + kgrp)]);
            acc2 = __builtin_amdgcn_mfma_f32_16x16x32_bf16(a, b, acc2, 0, 0, 0);
        }
        #pragma unroll
        for (int r = 0; r < 4; r += 2) {
            int grow = row0 + wave * 16 + crow0 + r;
            unsigned int pk = cvtpk(acc2[r] + bias2f, acc2[r + 1] + bias2f);
            Wallb[((size_t)m * NTOK + grow) * 16 + r16]     = (unsigned short)pk;
            Wallb[((size_t)m * NTOK + grow + 1) * 16 + r16] = (unsigned short)(pk >> 16);
        }
    }
}

// ---------------- kernel 3: ALL 12 scan steps, V slice in LDS (strided b32, reg-resident own V) ----
// Round-5 proven structure (stride-4B b32 reads, 0 bank conflicts) + three DS cuts:
//  * taps off=0 / 1024 / 2048 come from REGISTERS: thread owns tokens t=j*1024+tid, and
//    (t+1024)%4096 -> slot (j+1)&3, (t+2048)%4096 -> slot (j+2)&3  (Bv[] carries own V)
//  * ring pad shrinks to 512 tokens (max LDS tap = 512); pad write only j==0 & tid<512
// W(m+1) prefetched into registers during step m; batch pinned to XCD pair.
// Numerics bit-identical: bf16 V carry (RNE cvtpk), bf16 res steps 0..10, f32 resF +
// f32 out at step 11, same ascending-k FMA chain.
#define CCH 2
#define RPAD 512
#define PADTOK (SEQ + RPAD)             // 4608 tokens incl ring pad
__global__ __launch_bounds__(1024) void scan_lds_kernel(
    const unsigned short* __restrict__ resB,
    const float* __restrict__ resF,
    const unsigned short* __restrict__ Wallb,   // [NM][NTOK][16]
    float* __restrict__ outF)
{
    __shared__ unsigned int V32[2 * PADTOK];    // 36 KB

    const int bid = (int)blockIdx.x;
    const int bb    = (bid >> 1) & 3;                 // batch -> XCD pair
    const int chunk = ((bid >> 3) << 1) | (bid & 1);  // 0..63
    const int d0  = chunk * CCH;
    const int tid = threadIdx.x;                      // 0..1023

    // ---- one-time: res regs + own-V regs (Bv) + seed V0 (with ring pad) ----
    float resLo[4], resHi[4];
    unsigned int Bv[4];
    #pragma unroll
    for (int j = 0; j < 4; ++j) {
        int t = j * 1024 + tid;
        int n = (bb << 12) + t;
        unsigned int r = *reinterpret_cast<const unsigned int*>(resB + (size_t)n * DIM + d0);
        resLo[j] = uaf(r << 16);
        resHi[j] = uaf(r & 0xffff0000u);
        Bv[j] = r;
        V32[t] = r;
    }
    if (tid < RPAD) V32[SEQ + tid] = Bv[0];

    // ---- hoisted load: f32 res for the final step ----
    float2 rfv[4];
    #pragma unroll
    for (int j = 0; j < 4; ++j) {
        int n = (bb << 12) + j * 1024 + tid;
        rfv[j] = *reinterpret_cast<const float2*>(resF + (size_t)n * DIM + d0);
    }

    const unsigned short* wb0 = Wallb + (size_t)(bb << 12) * 16;

    // ---- preload W for step 0 ----
    uint4 wA[4][2];
    #pragma unroll
    for (int j = 0; j < 4; ++j) {
        const uint4* wrow = reinterpret_cast<const uint4*>(wb0 + (size_t)(j * 1024 + tid) * 16);
        wA[j][0] = wrow[0]; wA[j][1] = wrow[1];
    }
    __syncthreads();

    unsigned int curbase = 0;

    // ---- steps 0..10: bf16 V carry; W(m+1) prefetched during compute ----
    #pragma unroll 1
    for (int m = 0; m < NM - 1; ++m) {
        // issue next step's W loads first (consumed after compute -> latency hidden)
        uint4 wN[4][2];
        {
            const unsigned short* wpn = wb0 + (size_t)(m + 1) * NTOK * 16;
            #pragma unroll
            for (int j = 0; j < 4; ++j) {
                const uint4* wrow = reinterpret_cast<const uint4*>(wpn + (size_t)(j * 1024 + tid) * 16);
                wN[j][0] = wrow[0]; wN[j][1] = wrow[1];
            }
        }

        const unsigned int nb = curbase ^ PADTOK;
        float o0[4], o1[4];
        #pragma unroll
        for (int j = 0; j < 4; ++j) { o0[j] = resLo[j]; o1[j] = resHi[j]; }

        #pragma unroll
        for (int k = 0; k < NK; ++k) {
            #pragma unroll
            for (int j = 0; j < 4; ++j) {
                uint4 wa = wA[j][0], wbv = wA[j][1];
                unsigned int ww =
                    (k < 2) ? wa.x : (k < 4) ? wa.y : (k < 6) ? wa.z : (k < 8) ? wa.w :
                    (k < 10) ? wbv.x : (k < 12) ? wbv.y : wbv.z;
                float w = (k & 1) ? uaf(ww & 0xffff0000u) : uaf(ww << 16);
                unsigned int v;
                if (k == 0)       v = Bv[j];
                else if (k == 11) v = Bv[(j + 1) & 3];
                else if (k == 12) v = Bv[(j + 2) & 3];
                else              v = V32[curbase + j * 1024 + tid + (1 << (k - 1))];
                o0[j] = __builtin_fmaf(w, uaf(v << 16),          o0[j]);
                o1[j] = __builtin_fmaf(w, uaf(v & 0xffff0000u), o1[j]);
            }
        }

        #pragma unroll
        for (int j = 0; j < 4; ++j) {
            unsigned int pk = cvtpk(o0[j], o1[j]);
            Bv[j] = pk;
            V32[nb + j * 1024 + tid] = pk;
        }
        if (tid < RPAD) V32[nb + SEQ + tid] = Bv[0];

        // rotate prefetched W into place (vmcnt wait lands here, after compute)
        #pragma unroll
        for (int j = 0; j < 4; ++j) { wA[j][0] = wN[j][0]; wA[j][1] = wN[j][1]; }
        __syncthreads();
        curbase = nb;
    }

    // ---- final step m=11: f32 res (prefetched), f32 out; W already in wA ----
    {
        float o0[4], o1[4];
        #pragma unroll
        for (int j = 0; j < 4; ++j) { o0[j] = rfv[j].x; o1[j] = rfv[j].y; }

        #pragma unroll
        for (int k = 0; k < NK; ++k) {
            #pragma unroll
            for (int j = 0; j < 4; ++j) {
                uint4 wa = wA[j][0], wbv = wA[j][1];
                unsigned int ww =
                    (k < 2) ? wa.x : (k < 4) ? wa.y : (k < 6) ? wa.z : (k < 8) ? wa.w :
                    (k < 10) ? wbv.x : (k < 12) ? wbv.y : wbv.z;
                float w = (k & 1) ? uaf(ww & 0xffff0000u) : uaf(ww << 16);
                unsigned int v;
                if (k == 0)       v = Bv[j];
                else if (k == 11) v = Bv[(j + 1) & 3];
                else if (k == 12) v = Bv[(j + 2) & 3];
                else              v = V32[curbase + j * 1024 + tid + (1 << (k - 1))];
                o0[j] = __builtin_fmaf(w, uaf(v << 16),          o0[j]);
                o1[j] = __builtin_fmaf(w, uaf(v & 0xffff0000u), o1[j]);
            }
        }

        #pragma unroll
        for (int j = 0; j < 4; ++j) {
            int n = (bb << 12) + j * 1024 + tid;
            float2 o; o.x = o0[j]; o.y = o1[j];
            *reinterpret_cast<float2*>(outF + (size_t)n * DIM + d0) = o;
        }
    }
}

// ---------------- launch ----------------
extern "C" void kernel_launch(void* const* d_in, const int* in_sizes, int n_in,
                              void* d_out, int out_size, void* d_ws, size_t ws_size,
                              hipStream_t stream) {
    const int*   data = (const int*)  d_in[0];
    const float* emb  = (const float*)d_in[2];
    const float* apc  = (const float*)d_in[3];
    const float* g_W1 = (const float*)d_in[4];
    const float* g_b1 = (const float*)d_in[5];
    const float* g_W2 = (const float*)d_in[6];
    const float* g_b2 = (const float*)d_in[7];
    const float* f_W1 = (const float*)d_in[8];
    const float* f_b1 = (const float*)d_in[9];
    const float* f_W2 = (const float*)d_in[10];
    const float* f_b2 = (const float*)d_in[11];
    float* out = (float*)d_out;

    char* ws = (char*)d_ws;
    size_t off = 0;
    auto alloc = [&](size_t bytes) {
        void* p = ws + off;
        off += (bytes + 255) & ~(size_t)255;
        return p;
    };
    unsigned short* xb    = (unsigned short*)alloc((size_t)NTOK * DIM * 2);
    unsigned short* wb1T  = (unsigned short*)alloc((size_t)NSEG * DIM * DIM * 2);
    unsigned short* wb2Tg = (unsigned short*)alloc((size_t)DIM * DIM * 2);
    unsigned short* wb2Tf = (unsigned short*)alloc((size_t)NM * 16 * DIM * 2);
    float*          resF  = (float*)alloc((size_t)NTOK * DIM * 4);
    unsigned short* resB  = (unsigned short*)alloc((size_t)NTOK * DIM * 2);
    unsigned short* Wallb = (unsigned short*)alloc((size_t)NM * NTOK * 16 * 2);
    (void)ws_size; (void)in_sizes; (void)n_in; (void)out_size;

    prep_kernel<<<EMB_BLOCKS + CONV_BLOCKS, 256, 0, stream>>>(
        data, emb, apc, xb, g_W1, g_W2, f_W1, f_W2, wb1T, wb2Tg, wb2Tf);

    dim3 grid(NTOK / 64, NSEG);
    mlp_kernel<<<grid, 256, 0, stream>>>(xb, wb1T, wb2Tg, wb2Tf,
                                         g_b1, g_b2, f_b1, f_b2, resF, resB, Wallb);

    // all 12 scan steps in one kernel: strided-b32 LDS gathers (conflict-free),
    // own/±1024/±2048 taps from registers, W software-pipelined, batch->XCD pinned
    scan_lds_kernel<<<256, 1024, 0, stream>>>(resB, resF, Wallb, out);
}